// Round 1
// baseline (28128.925 us; speedup 1.0000x reference)
//
#include <hip/hip_runtime.h>

// Problem constants (fixed by the reference)
#define BATCH 256
#define TLEN  1000
#define HDIM  512

// Key structural fact: the recurrence is fully batch-independent (all matmuls
// are row-wise per batch; k-carry is per batch). So: one block per batch,
// h/h*r/k live in block-local LDS/registers, ZERO grid syncs, ZERO cross-block
// traffic. Weights (3.15 MB) stream from L2 (fits in 4 MiB/XCD) each step with
// perfectly coalesced per-row loads; 8 waves/CU read the same stream nearly in
// lockstep so L1 captures most cross-wave reuse.
__launch_bounds__(512, 1)
__global__ void mc_gru_batch_kernel(
    const float* __restrict__ inputs,  // (B, T)  [IN==1]
    const float* __restrict__ St,      // (B)
    const float* __restrict__ Mass,    // (B)
    const float* __restrict__ Wz,      // (513, 512) row-major
    const float* __restrict__ bz,      // (512)
    const float* __restrict__ Wr,      // (513, 512)
    const float* __restrict__ br,      // (512)
    const float* __restrict__ Wh,      // (515, 512)
    const float* __restrict__ bh,      // (512)
    const float* __restrict__ Wk,      // (513)
    const float* __restrict__ bk,      // (1)
    float* __restrict__ out)           // (B, T, H)
{
    __shared__ float x_l[TLEN];        // whole input row for this batch (4 KB)
    __shared__ float h_l[HDIM];        // h_{t-1}
    __shared__ float hr_l[HDIM];       // h * r
    __shared__ float kw_l[8];          // per-wave partials of h_new . Wk

    const int c = threadIdx.x;         // column 0..511
    const int b = blockIdx.x;          // batch 0..255

    // one-time staging: input row, h0 = 0
    for (int idx = c; idx < TLEN; idx += 512) x_l[idx] = inputs[b * TLEN + idx];
    h_l[c] = 0.0f;

    // per-thread time-invariant weights (first rows, tail rows, biases)
    const float wz0   = Wz[c];
    const float wr0   = Wr[c];
    const float wh0   = Wh[c];
    const float wh513 = Wh[513 * HDIM + c];
    const float wh514 = Wh[514 * HDIM + c];
    const float bzc   = bz[c];
    const float brc   = br[c];
    const float bhc   = bh[c];
    const float wkc   = Wk[c];
    const float wk512 = Wk[512];
    const float bk0   = bk[0];
    const float st    = St[b];
    const float mass  = Mass[b];

    // base pointers at row 1, own column
    const float* __restrict__ Wz1 = Wz + HDIM + c;
    const float* __restrict__ Wr1 = Wr + HDIM + c;
    const float* __restrict__ Wh1 = Wh + HDIM + c;

    float h_reg = 0.0f;                // own h element
    float k_reg = 0.0f;                // k carry (uniform across block)
    __syncthreads();

    for (int t = 0; t < TLEN; ++t) {
        const float x = x_l[t];

        // ---------- phase A: z, r gates (read h_l, stream Wz/Wr rows) ----------
        float az = x * wz0;
        float ar = x * wr0;
        const float4* h4 = (const float4*)h_l;
        #pragma unroll 4
        for (int k4 = 0; k4 < HDIM / 4; ++k4) {
            const float4 hv = h4[k4];            // uniform LDS read (broadcast)
            const int k = 4 * k4;
            az += hv.x * Wz1[(k + 0) * HDIM] + hv.y * Wz1[(k + 1) * HDIM]
                + hv.z * Wz1[(k + 2) * HDIM] + hv.w * Wz1[(k + 3) * HDIM];
            ar += hv.x * Wr1[(k + 0) * HDIM] + hv.y * Wr1[(k + 1) * HDIM]
                + hv.z * Wr1[(k + 2) * HDIM] + hv.w * Wr1[(k + 3) * HDIM];
        }
        const float z = 1.0f / (1.0f + __expf(-(az + bzc)));
        const float r = 1.0f / (1.0f + __expf(-(ar + brc)));
        hr_l[c] = h_reg * r;
        __syncthreads();                         // S1: hr_l published

        // ---------- phase B: candidate + state update (read hr_l, stream Wh) ----------
        float ah = x * wh0 + (st * k_reg) * wh513 + mass * wh514 + bhc;
        const float4* hr4 = (const float4*)hr_l;
        #pragma unroll 4
        for (int k4 = 0; k4 < HDIM / 4; ++k4) {
            const float4 hv = hr4[k4];
            const int k = 4 * k4;
            ah += hv.x * Wh1[(k + 0) * HDIM] + hv.y * Wh1[(k + 1) * HDIM]
                + hv.z * Wh1[(k + 2) * HDIM] + hv.w * Wh1[(k + 3) * HDIM];
        }
        const float e  = __expf(-2.0f * ah);
        const float ht = (1.0f - e) / (1.0f + e);        // tanh
        const float hn = (1.0f - z) * h_reg + z * ht;
        h_reg = hn;

        // non-temporal: keep the 512 KB/step output stream out of L2 so the
        // weights stay resident
        __builtin_nontemporal_store(hn, &out[(b * TLEN + t) * HDIM + c]);

        // publish h for next step (safe: phase-A reads finished before S1;
        // phase B reads only hr_l)
        h_l[c] = hn;

        // k partial: h_new . Wk, reduced across the block (wave shuffle + LDS)
        float kc = hn * wkc;
        kc += __shfl_xor(kc, 1);
        kc += __shfl_xor(kc, 2);
        kc += __shfl_xor(kc, 4);
        kc += __shfl_xor(kc, 8);
        kc += __shfl_xor(kc, 16);
        kc += __shfl_xor(kc, 32);
        if ((c & 63) == 0) kw_l[c >> 6] = kc;
        __syncthreads();                         // S2: h_l + kw_l published

        // k carry update, computed redundantly (uniform) by every thread
        const float ksum = kw_l[0] + kw_l[1] + kw_l[2] + kw_l[3]
                         + kw_l[4] + kw_l[5] + kw_l[6] + kw_l[7];
        k_reg = 1.0f / (1.0f + __expf(-(ksum + wk512 * k_reg + bk0)));
    }
}

extern "C" void kernel_launch(void* const* d_in, const int* in_sizes, int n_in,
                              void* d_out, int out_size, void* d_ws, size_t ws_size,
                              hipStream_t stream) {
    (void)in_sizes; (void)n_in; (void)out_size; (void)d_ws; (void)ws_size;

    const float* inputs = (const float*)d_in[0];
    const float* St     = (const float*)d_in[1];
    const float* Mass   = (const float*)d_in[2];
    const float* Wz     = (const float*)d_in[3];
    const float* bz     = (const float*)d_in[4];
    const float* Wr     = (const float*)d_in[5];
    const float* br     = (const float*)d_in[6];
    const float* Wh     = (const float*)d_in[7];
    const float* bh     = (const float*)d_in[8];
    const float* Wk     = (const float*)d_in[9];
    const float* bk     = (const float*)d_in[10];
    float* out = (float*)d_out;

    hipLaunchKernelGGL(mc_gru_batch_kernel, dim3(BATCH), dim3(512), 0, stream,
                       inputs, St, Mass, Wz, bz, Wr, br, Wh, bh, Wk, bk, out);
}